// Round 2
// 306.892 us; speedup vs baseline: 1.0709x; 1.0709x over previous
//
#include <hip/hip_runtime.h>
#include <hip/hip_bf16.h>
#include <math.h>

// GAT 2-layer fused pipeline for MI355X (gfx950).
// Round-11 (resubmit; round-1 bench was an infra container failure):
//   GEMM restructured for occupancy + single-pass A:
//   64-row blocks, 4 waves split ALL output columns (q and p together),
//   A staged once in LDS (hi/lo bf16, XOR-swizzled), W streamed from the
//   L2-resident packed buffers, LDS-bounce epilogue for full-line bf16
//   stores (removes the 1.9x WRITE_SIZE partial-line inflation).
// gat_agg restructured to 16-lanes-per-node (4 nodes/wave): 4-stage
//   row_ror butterfly reduce serves 4 edges at once; leaky(x)*a computed
//   as fma(d,0.6a)+fma(|d|,0.4a) using the free abs modifier.
// CSR build (atomic-free two-level counting sort) unchanged from r10.

#define SLOPE 0.2f

typedef __attribute__((ext_vector_type(8))) __bf16 bf16x8;
typedef __attribute__((ext_vector_type(4))) float f32x4;

__device__ __forceinline__ float gelu_erf(float x) {
    return 0.5f * x * (1.0f + erff(x * 0.70710678118654752f));
}

__device__ __forceinline__ unsigned short f2bf(float f) {  // RNE
    unsigned int u = __float_as_uint(f);
    return (unsigned short)((u + 0x7fffu + ((u >> 16) & 1u)) >> 16);
}
__device__ __forceinline__ float bf2f(unsigned short h) {
    return __uint_as_float((unsigned int)h << 16);
}

// XOR swizzle for LDS planes with 256B row stride: spreads the 16-row
// column slice of a ds_read_b128 across 8 distinct 16B slots.
__device__ __forceinline__ int swz(int off) { return off ^ ((off >> 4) & 0x70); }

// ---------------- weight prepack ---------------------------------------------
// Pack index i = ((ct*4+ks)*64 + lane)*8 + j  ->  W[k][n],
// k = ks*32 + (lane>>4)*8 + j,  n = ct*16 + (lane&15).  hi at [i], lo at [CE+i].
__global__ __launch_bounds__(256) void pack_w(
    const float* __restrict__ W0,  const float* __restrict__ Wq1,
    const float* __restrict__ Wp1, const float* __restrict__ Wq2,
    const float* __restrict__ Wp2,
    unsigned short* __restrict__ P0,  unsigned short* __restrict__ Pq1,
    unsigned short* __restrict__ Pp1, unsigned short* __restrict__ Pq2,
    unsigned short* __restrict__ Pp2)
{
    const float* W; unsigned short* P; int C;
    switch (blockIdx.y) {
        case 0:  W = W0;  P = P0;  C = 128; break;
        case 1:  W = Wq1; P = Pq1; C = 128; break;
        case 2:  W = Wp1; P = Pp1; C = 128; break;
        case 3:  W = Wq2; P = Pq2; C = 64;  break;
        default: W = Wp2; P = Pp2; C = 64;  break;
    }
    int i = blockIdx.x * 256 + threadIdx.x;
    int CE = C * 128;
    if (i >= CE) return;
    int j = i & 7, l = (i >> 3) & 63, ks = (i >> 9) & 3, ct = i >> 11;
    int k = ks * 32 + ((l >> 4) << 3) + j;
    int n = ct * 16 + (l & 15);
    float v = W[k * C + n];
    unsigned short hb = f2bf(v);
    P[i] = hb;
    P[CE + i] = f2bf(v - bf2f(hb));
}

// ---------------- MFMA GEMM -------------------------------------------------
// Block = 64 rows x ALL output cols; 4 waves split the col-tiles.
// A panel (64x128, hi+lo bf16 = 32 KB) staged in LDS once (swizzled);
// W fragments streamed from packed global (L2-resident).
// EPI 0: single matrix, out = gelu -> o1hi/o1lo (layer 0, A = fp32).
// EPI 1: TWO matrices: waves 0-1 -> q fp32 (direct), waves 2-3 -> p bf16
//        (LDS-bounced for coalesced 16B stores).
template <int C, bool TWO, int EPI>
__global__ __launch_bounds__(256) void mfma_gemm(
    const float* __restrict__ Af,
    const unsigned short* __restrict__ AHg, const unsigned short* __restrict__ ALg,
    const unsigned short* __restrict__ P1, const float* __restrict__ b1,
    const unsigned short* __restrict__ P2, const float* __restrict__ b2,
    float* __restrict__ outq, unsigned short* __restrict__ outp,
    unsigned short* __restrict__ o1hi, unsigned short* __restrict__ o1lo,
    int N)
{
    constexpr int CE  = C * 128;
    constexpr int CTT = (TWO ? 2 : 1) * (C / 16);   // total col-tiles
    constexpr int CTW = CTT / 4;                    // tiles per wave
    constexpr int QCT = C / 16;                     // tiles in first matrix

    __shared__ __align__(16) unsigned char lds[32768]; // hi plane [0,16K), lo [16K,32K)

    const int t = threadIdx.x;
    const int lane = t & 63;
    const int w = t >> 6;
    const int row0 = blockIdx.x * 64;
    const int mcol = lane & 15;
    const int hk = lane >> 4;

    // ---- stage A (64 rows x 128 dims) as hi/lo bf16 into LDS ----
    if constexpr (EPI == 0) {
#pragma unroll
        for (int i = 0; i < 8; i++) {
            int idx = t + i * 256;            // float4 index, 2048 total
            int row = idx >> 5;               // 32 float4 per row
            int gr = row0 + row;
            float4 v = make_float4(0.f, 0.f, 0.f, 0.f);
            if (gr < N) v = *reinterpret_cast<const float4*>(Af + (size_t)gr * 128 + (idx & 31) * 4);
            const float* f = reinterpret_cast<const float*>(&v);
            unsigned int h[4], l[4];
#pragma unroll
            for (int j = 0; j < 4; j++) {
                unsigned short hb = f2bf(f[j]);
                h[j] = hb;
                l[j] = f2bf(f[j] - bf2f(hb));
            }
            int so = swz(row * 256 + (idx & 31) * 8);
            *reinterpret_cast<uint2*>(&lds[so])         = make_uint2(h[0] | (h[1] << 16), h[2] | (h[3] << 16));
            *reinterpret_cast<uint2*>(&lds[16384 + so]) = make_uint2(l[0] | (l[1] << 16), l[2] | (l[3] << 16));
        }
    } else {
#pragma unroll
        for (int i = 0; i < 4; i++) {
            int idx = t + i * 256;            // uint4 index, 1024 per plane
            int row = idx >> 4;               // 16 uint4 per row
            int gr = row0 + row;
            uint4 vh = make_uint4(0, 0, 0, 0), vl = make_uint4(0, 0, 0, 0);
            if (gr < N) {
                vh = *reinterpret_cast<const uint4*>(AHg + (size_t)gr * 128 + (idx & 15) * 8);
                vl = *reinterpret_cast<const uint4*>(ALg + (size_t)gr * 128 + (idx & 15) * 8);
            }
            int so = swz(row * 256 + (idx & 15) * 16);
            *reinterpret_cast<uint4*>(&lds[so])         = vh;
            *reinterpret_cast<uint4*>(&lds[16384 + so]) = vl;
        }
    }
    __syncthreads();

    f32x4 acc[CTW][4];
#pragma unroll
    for (int c = 0; c < CTW; c++)
#pragma unroll
        for (int rf = 0; rf < 4; rf++) acc[c][rf] = (f32x4){0.f, 0.f, 0.f, 0.f};

#pragma unroll
    for (int ks = 0; ks < 4; ks++) {
        bf16x8 ah[4], al[4];
#pragma unroll
        for (int rf = 0; rf < 4; rf++) {
            int so = swz((rf * 16 + mcol) * 256 + ks * 64 + hk * 16);
            ah[rf] = *reinterpret_cast<const bf16x8*>(&lds[so]);
            al[rf] = *reinterpret_cast<const bf16x8*>(&lds[16384 + so]);
        }
#pragma unroll
        for (int c = 0; c < CTW; c++) {
            int ctg = w * CTW + c;
            bool isq = (!TWO) || (ctg < QCT);
            int ct = isq ? ctg : ctg - QCT;
            const unsigned short* P = isq ? P1 : P2;
            const unsigned short* Wp = P + ((ct * 4 + ks) * 64 + lane) * 8;
            bf16x8 bh = *reinterpret_cast<const bf16x8*>(Wp);
            bf16x8 bl = *reinterpret_cast<const bf16x8*>(Wp + CE);
#pragma unroll
            for (int rf = 0; rf < 4; rf++) {
                acc[c][rf] = __builtin_amdgcn_mfma_f32_16x16x32_bf16(ah[rf], bh, acc[c][rf], 0, 0, 0);
                acc[c][rf] = __builtin_amdgcn_mfma_f32_16x16x32_bf16(al[rf], bh, acc[c][rf], 0, 0, 0);
                acc[c][rf] = __builtin_amdgcn_mfma_f32_16x16x32_bf16(ah[rf], bl, acc[c][rf], 0, 0, 0);
            }
        }
    }

    __syncthreads();   // all A ds_reads done; LDS reused for epilogue staging

    // epilogue: C/D layout col=lane&15, row=(lane>>4)*4+reg
    if constexpr (EPI == 0) {
#pragma unroll
        for (int c = 0; c < CTW; c++) {
            int col = (w * CTW + c) * 16 + mcol;
            float bv = b1[col];
#pragma unroll
            for (int rf = 0; rf < 4; rf++) {
#pragma unroll
                for (int r = 0; r < 4; r++) {
                    int row = rf * 16 + hk * 4 + r;
                    float v = gelu_erf(acc[c][rf][r] + bv);
                    unsigned short hb = f2bf(v);
                    int bo = row * 256 + col * 2;
                    *reinterpret_cast<unsigned short*>(&lds[swz(bo)])         = hb;
                    *reinterpret_cast<unsigned short*>(&lds[16384 + swz(bo)]) = f2bf(v - bf2f(hb));
                }
            }
        }
        __syncthreads();
#pragma unroll
        for (int i = 0; i < 8; i++) {
            int idx = t + i * 256;          // 2048 uint4: hi 0..1023, lo 1024..2047
            int pl = idx >> 10;
            int j = idx & 1023;
            int row = j >> 4;
            int gr = row0 + row;
            if (gr < N) {
                uint4 v = *reinterpret_cast<const uint4*>(&lds[pl * 16384 + swz(row * 256 + (j & 15) * 16)]);
                unsigned short* dp = pl ? o1lo : o1hi;
                *reinterpret_cast<uint4*>(dp + (size_t)gr * 128 + (j & 15) * 8) = v;
            }
        }
    } else {
#pragma unroll
        for (int c = 0; c < CTW; c++) {
            int ctg = w * CTW + c;
            bool isq = ctg < QCT;
            int ct = isq ? ctg : ctg - QCT;
            int col = ct * 16 + mcol;
            float bv = (isq ? b1 : b2)[col];
#pragma unroll
            for (int rf = 0; rf < 4; rf++) {
#pragma unroll
                for (int r = 0; r < 4; r++) {
                    int row = rf * 16 + hk * 4 + r;
                    int gr = row0 + row;
                    float v = acc[c][rf][r] + bv;
                    if (isq) {
                        if (gr < N) outq[(size_t)gr * C + col] = v;   // 4B x 16 lanes = full line
                    } else {
                        *reinterpret_cast<unsigned short*>(&lds[swz(row * 256 + col * 2)]) = f2bf(v);
                    }
                }
            }
        }
        __syncthreads();
        constexpr int SLOTS = C / 8;        // uint4 slots per row (16 or 8)
#pragma unroll
        for (int i = 0; i < (64 * SLOTS) / 256; i++) {
            int idx = t + i * 256;
            int row = idx / SLOTS;
            int sl = idx % SLOTS;
            int gr = row0 + row;
            if (gr < N)
                *reinterpret_cast<uint4*>(outp + (size_t)gr * C + sl * 8) =
                    *reinterpret_cast<const uint4*>(&lds[swz(row * 256 + sl * 16)]);
        }
    }
}

// ---------------- CSR build: atomic-free two-level counting sort -------------
// Coarse bin = dst >> 4 (16 nodes per bin), CB = ceil(N/16) <= 4096.
// 64 edge-blocks; gh[bin*64 + blk] = count (bin-major for linear scan).

__global__ __launch_bounds__(256) void hist_coarse(
    const int* __restrict__ dst, int* __restrict__ gh, int E, int CB)
{
    __shared__ int cnt[4096];
    const int blk = blockIdx.x;     // 0..63
    const int t = threadIdx.x;
    for (int b = t; b < CB; b += 256) cnt[b] = 0;
    __syncthreads();
    const int epb = (E + 63) / 64;
    const int s = blk * epb;
    const int e_ = (s + epb < E) ? s + epb : E;
    for (int i = s + t; i < e_; i += 256)
        atomicAdd(&cnt[dst[i] >> 4], 1);
    __syncthreads();
    for (int b = t; b < CB; b += 256)
        gh[b * 64 + blk] = cnt[b];
}

// hierarchical exclusive scan over M = CB*64 values: gh -> gscan
__global__ __launch_bounds__(256) void scan1_kernel(const int* __restrict__ gh,
                                                    int* __restrict__ gscan,
                                                    int* __restrict__ bsum, int M)
{
    __shared__ int lds[256];
    int t = threadIdx.x;
    int i = blockIdx.x * 256 + t;
    int v = (i < M) ? gh[i] : 0;
    lds[t] = v;
    __syncthreads();
    int x = v;
    for (int off = 1; off < 256; off <<= 1) {
        int y = (t >= off) ? lds[t - off] : 0;
        __syncthreads();
        x += y;
        lds[t] = x;
        __syncthreads();
    }
    if (i < M) gscan[i] = x - v;
    if (t == 255) bsum[blockIdx.x] = x;
}

__global__ __launch_bounds__(1024) void scan2_kernel(int* __restrict__ bsum, int NB)
{
    __shared__ int lds[1024];
    int t = threadIdx.x;
    int v = (t < NB) ? bsum[t] : 0;
    lds[t] = v;
    __syncthreads();
    int x = v;
    for (int off = 1; off < 1024; off <<= 1) {
        int y = (t >= off) ? lds[t - off] : 0;
        __syncthreads();
        x += y;
        lds[t] = x;
        __syncthreads();
    }
    if (t < NB) bsum[t] = x - v;
}

__global__ __launch_bounds__(256) void scan3_kernel(int* __restrict__ gscan,
                                                    const int* __restrict__ bsum, int M)
{
    int i = blockIdx.x * 256 + threadIdx.x;
    if (i < M) gscan[i] += bsum[blockIdx.x];
}

// scatter edges into coarse-bin-grouped (dst,src) pairs; LDS cursors only.
__global__ __launch_bounds__(256) void scatter_coarse(
    const int* __restrict__ src, const int* __restrict__ dst,
    const int* __restrict__ gscan, int2* __restrict__ pairs, int E, int CB)
{
    __shared__ int cur[4096];
    const int blk = blockIdx.x;     // 0..63
    const int t = threadIdx.x;
    for (int b = t; b < CB; b += 256)
        cur[b] = gscan[b * 64 + blk];
    __syncthreads();
    const int epb = (E + 63) / 64;
    const int s = blk * epb;
    const int e_ = (s + epb < E) ? s + epb : E;
    for (int i = s + t; i < e_; i += 256) {
        int d = dst[i];
        int sv = src[i];
        int pos = atomicAdd(&cur[d >> 4], 1);   // LDS atomic
        pairs[pos] = make_int2(d, sv);
    }
}

// one block per coarse bin: exact CSR within the bin's contiguous segment.
__global__ __launch_bounds__(256) void finalize_kernel(
    const int2* __restrict__ pairs, const int* __restrict__ gscan,
    int* __restrict__ offs, int* __restrict__ csr_src, int N, int E, int CB)
{
    const int c = blockIdx.x;
    const int t = threadIdx.x;
    __shared__ unsigned int cnt[8], rnk[8];
    __shared__ int pref[16];
    if (t < 8) { cnt[t] = 0u; rnk[t] = 0u; }
    __syncthreads();

    const int s  = gscan[c * 64];
    const int e_ = (c + 1 < CB) ? gscan[(c + 1) * 64] : E;
    const int base = c * 16;

    for (int i = s + t; i < e_; i += 256) {
        int d = pairs[i].x - base;    // 0..15
        atomicAdd(&cnt[d >> 1], 1u << ((d & 1) * 16));
    }
    __syncthreads();
    if (t == 0) {
        int run = s;
        for (int j = 0; j < 16; j++) {
            pref[j] = run;
            run += (int)((cnt[j >> 1] >> ((j & 1) * 16)) & 0xffffu);
        }
    }
    __syncthreads();
    if (t < 16 && base + t < N) offs[base + t] = pref[t];
    if (c == CB - 1 && t == 0) offs[N] = E;

    for (int i = s + t; i < e_; i += 256) {
        int2 pr = pairs[i];
        int d = pr.x - base;
        unsigned int old = atomicAdd(&rnk[d >> 1], 1u << ((d & 1) * 16));
        int r = (int)((old >> ((d & 1) * 16)) & 0xffffu);
        csr_src[pref[d] + r] = pr.y;
    }
}

// ---------------- fused GAT edge-softmax + aggregation -----------------------
// 16 lanes per dst node, 4 nodes per wave. Per edge-iteration each active
// group gathers its src row (uint4/uint2 per lane), computes the score
// partial as fma(d,0.6a)+fma(|d|,0.4a) (leaky(x)=0.6x+0.4|x|), then one
// shared 4-stage row_ror butterfly reduces all 4 groups simultaneously.
// EPI 0 (D=128): m2 = gelu(h+bvec) -> hi/lo bf16.  EPI 1 (D=64): fp32 out.
template <int D, int EPI>
__global__ __launch_bounds__(256) void gat_agg(
    const float* __restrict__ q, const unsigned short* __restrict__ p,
    const float* __restrict__ a, const float* __restrict__ bvec,
    const int* __restrict__ offs, const int* __restrict__ csr_src,
    float* __restrict__ out, unsigned short* __restrict__ mhi,
    unsigned short* __restrict__ mlo, int N)
{
    constexpr int VPL = D / 16;   // dims per lane: 8 (D=128) or 4 (D=64)
    const int t = threadIdx.x;
    const int lane = t & 63;
    const int sl = lane & 15;
    const int base = sl * VPL;
    const int node = blockIdx.x * 16 + ((t >> 6) << 2) + (lane >> 4);
    const bool valid = node < N;

    float qv[VPL], a6[VPL], a4[VPL], acc[VPL], pv[VPL];
#pragma unroll
    for (int v = 0; v < VPL; v++) { qv[v] = 0.f; acc[v] = 0.f; }
    if (valid) {
        const float* qp = q + (size_t)node * D + base;
        float4 q0 = *reinterpret_cast<const float4*>(qp);
        qv[0] = q0.x; qv[1] = q0.y; qv[2] = q0.z; qv[3] = q0.w;
        if constexpr (VPL == 8) {
            float4 q1 = *reinterpret_cast<const float4*>(qp + 4);
            qv[4] = q1.x; qv[5] = q1.y; qv[6] = q1.z; qv[7] = q1.w;
        }
    }
#pragma unroll
    for (int v = 0; v < VPL; v++) {
        float av = a[base + v];
        a6[v] = 0.6f * av;
        a4[v] = 0.4f * av;
    }

    float denom = 0.f;
    int e  = valid ? offs[node] : 0;
    int e1 = valid ? offs[node + 1] : 0;

    while (__any(e < e1)) {
        bool act = e < e1;
        float pa = 0.f;
        if (act) {
            int s0 = csr_src[e];
            if constexpr (D == 128) {
                uint4 u = *reinterpret_cast<const uint4*>(p + (size_t)s0 * 128 + base);
                pv[0] = __uint_as_float(u.x << 16); pv[1] = __uint_as_float(u.x & 0xffff0000u);
                pv[2] = __uint_as_float(u.y << 16); pv[3] = __uint_as_float(u.y & 0xffff0000u);
                pv[4] = __uint_as_float(u.z << 16); pv[5] = __uint_as_float(u.z & 0xffff0000u);
                pv[6] = __uint_as_float(u.w << 16); pv[7] = __uint_as_float(u.w & 0xffff0000u);
            } else {
                uint2 u = *reinterpret_cast<const uint2*>(p + (size_t)s0 * 64 + base);
                pv[0] = __uint_as_float(u.x << 16); pv[1] = __uint_as_float(u.x & 0xffff0000u);
                pv[2] = __uint_as_float(u.y << 16); pv[3] = __uint_as_float(u.y & 0xffff0000u);
            }
#pragma unroll
            for (int v = 0; v < VPL; v++) {
                float d = qv[v] + pv[v];
                pa = fmaf(d, a6[v], pa);
                pa = fmaf(fabsf(d), a4[v], pa);   // abs is a free VOP3 modifier
            }
        }
        // 16-lane all-reduce (row_ror 1,2,4,8): serves all 4 groups at once;
        // inactive lanes contribute 0.
        pa += __int_as_float(__builtin_amdgcn_update_dpp(0, __float_as_int(pa), 0x121, 0xF, 0xF, true));
        pa += __int_as_float(__builtin_amdgcn_update_dpp(0, __float_as_int(pa), 0x122, 0xF, 0xF, true));
        pa += __int_as_float(__builtin_amdgcn_update_dpp(0, __float_as_int(pa), 0x124, 0xF, 0xF, true));
        pa += __int_as_float(__builtin_amdgcn_update_dpp(0, __float_as_int(pa), 0x128, 0xF, 0xF, true));
        if (act) {
            float es = __expf(pa);
            denom += es;
#pragma unroll
            for (int v = 0; v < VPL; v++) acc[v] = fmaf(es, pv[v], acc[v]);
        }
        e++;
    }

    if (!valid) return;
    float inv = (denom != 0.f) ? 1.f / denom : 0.f;  // zero-degree -> agg = 0
    if constexpr (EPI == 0) {
        union { unsigned short us[8]; uint4 v; } H, L;
#pragma unroll
        for (int v = 0; v < VPL; v++) {
            float g = gelu_erf(acc[v] * inv + bvec[base + v]);
            H.us[v] = f2bf(g);
            L.us[v] = f2bf(g - bf2f(H.us[v]));
        }
        *reinterpret_cast<uint4*>(mhi + (size_t)node * 128 + base) = H.v;
        *reinterpret_cast<uint4*>(mlo + (size_t)node * 128 + base) = L.v;
    } else {
        union { float f[4]; float4 v; } O;
#pragma unroll
        for (int v = 0; v < VPL; v++) O.f[v] = acc[v] * inv + bvec[base + v];
        *reinterpret_cast<float4*>(out + (size_t)node * D + base) = O.v;
    }
}

// ---------------- launch ------------------------------------------------------
extern "C" void kernel_launch(void* const* d_in, const int* in_sizes, int n_in,
                              void* d_out, int out_size, void* d_ws, size_t ws_size,
                              hipStream_t stream)
{
    const float* x     = (const float*)d_in[0];
    const float* W0    = (const float*)d_in[1];
    const float* b0    = (const float*)d_in[2];
    const float* Wq1   = (const float*)d_in[3];
    const float* bq1   = (const float*)d_in[4];
    const float* Wp1   = (const float*)d_in[5];
    const float* bp1   = (const float*)d_in[6];
    const float* a1    = (const float*)d_in[7];
    const float* bg2   = (const float*)d_in[8];
    const float* Wq2   = (const float*)d_in[9];
    const float* bq2   = (const float*)d_in[10];
    const float* Wp2   = (const float*)d_in[11];
    const float* bp2   = (const float*)d_in[12];
    const float* a2    = (const float*)d_in[13];
    const float* b_out = (const float*)d_in[14];
    const int*   src   = (const int*)d_in[15];
    const int*   dst   = (const int*)d_in[16];

    const int N = in_sizes[0] / 128;
    const int E = in_sizes[15];
    float* out = (float*)d_out;

    // workspace carve
    float* q_buf        = (float*)d_ws;                      // N*128 f32
    unsigned short* pb  = (unsigned short*)(q_buf + (size_t)N * 128);  // N*128 bf16
    unsigned short* Mhi = pb + (size_t)N * 128;
    unsigned short* Mlo = Mhi + (size_t)N * 128;
    unsigned short* P0  = Mlo + (size_t)N * 128;
    unsigned short* Pq1 = P0  + 128 * 128 * 2;
    unsigned short* Pp1 = Pq1 + 128 * 128 * 2;
    unsigned short* Pq2 = Pp1 + 128 * 128 * 2;
    unsigned short* Pp2 = Pq2 + 128 * 64 * 2;
    int* offs    = (int*)(Pp2 + 128 * 64 * 2);
    int* csr_src = offs + (N + 2);
    const int CB = (N + 15) / 16;          // coarse bins (<= 4096 for N<=65536)
    const int M  = CB * 64;
    int* gh    = csr_src + E;
    int* gscan = gh + M;
    int* bsum  = gscan + M;                // 1024 ints
    // pairs aliases q_buf (dead until gemm layer-1); int2-aligned (base of ws)
    int2* pairs = (int2*)q_buf;

    const int NB1 = (M + 255) / 256;       // <= 1024

    // 1) weight prepack
    pack_w<<<dim3(64, 5), 256, 0, stream>>>(W0, Wq1, Wp1, Wq2, Wp2,
                                            P0, Pq1, Pp1, Pq2, Pp2);
    // 2-7) CSR build (atomic-free two-level counting sort)
    hist_coarse<<<64, 256, 0, stream>>>(dst, gh, E, CB);
    scan1_kernel<<<NB1, 256, 0, stream>>>(gh, gscan, bsum, M);
    scan2_kernel<<<1, 1024, 0, stream>>>(bsum, NB1);
    scan3_kernel<<<NB1, 256, 0, stream>>>(gscan, bsum, M);
    scatter_coarse<<<64, 256, 0, stream>>>(src, dst, gscan, pairs, E, CB);
    finalize_kernel<<<CB, 256, 0, stream>>>(pairs, gscan, offs, csr_src, N, E, CB);

    const int GB64 = (N + 63) / 64;
    const int GGAT = (N + 15) / 16;

    // 8) layer 0: m1 = gelu(x@W0 + b0) -> Mhi/Mlo
    mfma_gemm<128, false, 0><<<GB64, 256, 0, stream>>>(
        x, nullptr, nullptr, P0, b0, nullptr, nullptr,
        nullptr, nullptr, Mhi, Mlo, N);
    // 9) layer 1 projections: q1 fp32 + p1 bf16 in ONE pass over A
    mfma_gemm<128, true, 1><<<GB64, 256, 0, stream>>>(
        nullptr, Mhi, Mlo, Pq1, bq1, Pp1, bp1,
        q_buf, pb, nullptr, nullptr, N);
    // 10) layer 1 GAT -> m2 = gelu(h1 + bg2) -> Mhi/Mlo
    gat_agg<128, 0><<<GGAT, 256, 0, stream>>>(
        q_buf, pb, a1, bg2, offs, csr_src,
        nullptr, Mhi, Mlo, N);
    // 11) layer 2 projections: q2 fp32 + p2 bf16 in ONE pass over A
    mfma_gemm<64, true, 1><<<GB64, 256, 0, stream>>>(
        nullptr, Mhi, Mlo, Pq2, bq2, Pp2, bp2,
        q_buf, pb, nullptr, nullptr, N);
    // 12) layer 2 GAT + b_out -> d_out
    gat_agg<64, 1><<<GGAT, 256, 0, stream>>>(
        q_buf, pb, a2, b_out, offs, csr_src,
        out, nullptr, nullptr, N);
}

// Round 3
// 284.563 us; speedup vs baseline: 1.1549x; 1.0785x over previous
//
#include <hip/hip_runtime.h>
#include <hip/hip_bf16.h>
#include <math.h>

// GAT 2-layer fused pipeline for MI355X (gfx950).
// Round-12: gat_agg keeps the 16-lanes-per-node layout from r11 but
// restores 4-edge-per-iteration MLP (r11 regression root-cause: one
// serialized csr->gather chain per iteration starved the pipe; VALUBusy
// 77.7% -> 52%). Now: 4 independent csr loads + 4 independent p-row
// gathers in flight per group iteration + next-iteration csr prefetch;
// 4 independent DPP row-reduce chains. Inactive slots masked branchlessly.
// GEMM (64-row blocks, single-pass A, LDS-bounce epilogue) and CSR build
// unchanged from r11.

#define SLOPE 0.2f

typedef __attribute__((ext_vector_type(8))) __bf16 bf16x8;
typedef __attribute__((ext_vector_type(4))) float f32x4;

__device__ __forceinline__ float gelu_erf(float x) {
    return 0.5f * x * (1.0f + erff(x * 0.70710678118654752f));
}

__device__ __forceinline__ unsigned short f2bf(float f) {  // RNE
    unsigned int u = __float_as_uint(f);
    return (unsigned short)((u + 0x7fffu + ((u >> 16) & 1u)) >> 16);
}
__device__ __forceinline__ float bf2f(unsigned short h) {
    return __uint_as_float((unsigned int)h << 16);
}

// 16-lane (row) all-reduce sum via DPP row_ror 1,2,4,8; every lane of the
// row ends with the row's sum. Chains over different inputs are independent.
__device__ __forceinline__ float row16_sum(float x) {
    x += __int_as_float(__builtin_amdgcn_update_dpp(0, __float_as_int(x), 0x121, 0xF, 0xF, true));
    x += __int_as_float(__builtin_amdgcn_update_dpp(0, __float_as_int(x), 0x122, 0xF, 0xF, true));
    x += __int_as_float(__builtin_amdgcn_update_dpp(0, __float_as_int(x), 0x124, 0xF, 0xF, true));
    x += __int_as_float(__builtin_amdgcn_update_dpp(0, __float_as_int(x), 0x128, 0xF, 0xF, true));
    return x;
}

// XOR swizzle for LDS planes with 256B row stride: spreads the 16-row
// column slice of a ds_read_b128 across 8 distinct 16B slots.
__device__ __forceinline__ int swz(int off) { return off ^ ((off >> 4) & 0x70); }

// ---------------- weight prepack ---------------------------------------------
// Pack index i = ((ct*4+ks)*64 + lane)*8 + j  ->  W[k][n],
// k = ks*32 + (lane>>4)*8 + j,  n = ct*16 + (lane&15).  hi at [i], lo at [CE+i].
__global__ __launch_bounds__(256) void pack_w(
    const float* __restrict__ W0,  const float* __restrict__ Wq1,
    const float* __restrict__ Wp1, const float* __restrict__ Wq2,
    const float* __restrict__ Wp2,
    unsigned short* __restrict__ P0,  unsigned short* __restrict__ Pq1,
    unsigned short* __restrict__ Pp1, unsigned short* __restrict__ Pq2,
    unsigned short* __restrict__ Pp2)
{
    const float* W; unsigned short* P; int C;
    switch (blockIdx.y) {
        case 0:  W = W0;  P = P0;  C = 128; break;
        case 1:  W = Wq1; P = Pq1; C = 128; break;
        case 2:  W = Wp1; P = Pp1; C = 128; break;
        case 3:  W = Wq2; P = Pq2; C = 64;  break;
        default: W = Wp2; P = Pp2; C = 64;  break;
    }
    int i = blockIdx.x * 256 + threadIdx.x;
    int CE = C * 128;
    if (i >= CE) return;
    int j = i & 7, l = (i >> 3) & 63, ks = (i >> 9) & 3, ct = i >> 11;
    int k = ks * 32 + ((l >> 4) << 3) + j;
    int n = ct * 16 + (l & 15);
    float v = W[k * C + n];
    unsigned short hb = f2bf(v);
    P[i] = hb;
    P[CE + i] = f2bf(v - bf2f(hb));
}

// ---------------- MFMA GEMM -------------------------------------------------
// Block = 64 rows x ALL output cols; 4 waves split the col-tiles.
// A panel (64x128, hi+lo bf16 = 32 KB) staged in LDS once (swizzled);
// W fragments streamed from packed global (L2-resident).
// EPI 0: single matrix, out = gelu -> o1hi/o1lo (layer 0, A = fp32).
// EPI 1: TWO matrices: waves 0-1 -> q fp32 (direct), waves 2-3 -> p bf16
//        (LDS-bounced for coalesced 16B stores).
template <int C, bool TWO, int EPI>
__global__ __launch_bounds__(256) void mfma_gemm(
    const float* __restrict__ Af,
    const unsigned short* __restrict__ AHg, const unsigned short* __restrict__ ALg,
    const unsigned short* __restrict__ P1, const float* __restrict__ b1,
    const unsigned short* __restrict__ P2, const float* __restrict__ b2,
    float* __restrict__ outq, unsigned short* __restrict__ outp,
    unsigned short* __restrict__ o1hi, unsigned short* __restrict__ o1lo,
    int N)
{
    constexpr int CE  = C * 128;
    constexpr int CTT = (TWO ? 2 : 1) * (C / 16);   // total col-tiles
    constexpr int CTW = CTT / 4;                    // tiles per wave
    constexpr int QCT = C / 16;                     // tiles in first matrix

    __shared__ __align__(16) unsigned char lds[32768]; // hi plane [0,16K), lo [16K,32K)

    const int t = threadIdx.x;
    const int lane = t & 63;
    const int w = t >> 6;
    const int row0 = blockIdx.x * 64;
    const int mcol = lane & 15;
    const int hk = lane >> 4;

    // ---- stage A (64 rows x 128 dims) as hi/lo bf16 into LDS ----
    if constexpr (EPI == 0) {
#pragma unroll
        for (int i = 0; i < 8; i++) {
            int idx = t + i * 256;            // float4 index, 2048 total
            int row = idx >> 5;               // 32 float4 per row
            int gr = row0 + row;
            float4 v = make_float4(0.f, 0.f, 0.f, 0.f);
            if (gr < N) v = *reinterpret_cast<const float4*>(Af + (size_t)gr * 128 + (idx & 31) * 4);
            const float* f = reinterpret_cast<const float*>(&v);
            unsigned int h[4], l[4];
#pragma unroll
            for (int j = 0; j < 4; j++) {
                unsigned short hb = f2bf(f[j]);
                h[j] = hb;
                l[j] = f2bf(f[j] - bf2f(hb));
            }
            int so = swz(row * 256 + (idx & 31) * 8);
            *reinterpret_cast<uint2*>(&lds[so])         = make_uint2(h[0] | (h[1] << 16), h[2] | (h[3] << 16));
            *reinterpret_cast<uint2*>(&lds[16384 + so]) = make_uint2(l[0] | (l[1] << 16), l[2] | (l[3] << 16));
        }
    } else {
#pragma unroll
        for (int i = 0; i < 4; i++) {
            int idx = t + i * 256;            // uint4 index, 1024 per plane
            int row = idx >> 4;               // 16 uint4 per row
            int gr = row0 + row;
            uint4 vh = make_uint4(0, 0, 0, 0), vl = make_uint4(0, 0, 0, 0);
            if (gr < N) {
                vh = *reinterpret_cast<const uint4*>(AHg + (size_t)gr * 128 + (idx & 15) * 8);
                vl = *reinterpret_cast<const uint4*>(ALg + (size_t)gr * 128 + (idx & 15) * 8);
            }
            int so = swz(row * 256 + (idx & 15) * 16);
            *reinterpret_cast<uint4*>(&lds[so])         = vh;
            *reinterpret_cast<uint4*>(&lds[16384 + so]) = vl;
        }
    }
    __syncthreads();

    f32x4 acc[CTW][4];
#pragma unroll
    for (int c = 0; c < CTW; c++)
#pragma unroll
        for (int rf = 0; rf < 4; rf++) acc[c][rf] = (f32x4){0.f, 0.f, 0.f, 0.f};

#pragma unroll
    for (int ks = 0; ks < 4; ks++) {
        bf16x8 ah[4], al[4];
#pragma unroll
        for (int rf = 0; rf < 4; rf++) {
            int so = swz((rf * 16 + mcol) * 256 + ks * 64 + hk * 16);
            ah[rf] = *reinterpret_cast<const bf16x8*>(&lds[so]);
            al[rf] = *reinterpret_cast<const bf16x8*>(&lds[16384 + so]);
        }
#pragma unroll
        for (int c = 0; c < CTW; c++) {
            int ctg = w * CTW + c;
            bool isq = (!TWO) || (ctg < QCT);
            int ct = isq ? ctg : ctg - QCT;
            const unsigned short* P = isq ? P1 : P2;
            const unsigned short* Wp = P + ((ct * 4 + ks) * 64 + lane) * 8;
            bf16x8 bh = *reinterpret_cast<const bf16x8*>(Wp);
            bf16x8 bl = *reinterpret_cast<const bf16x8*>(Wp + CE);
#pragma unroll
            for (int rf = 0; rf < 4; rf++) {
                acc[c][rf] = __builtin_amdgcn_mfma_f32_16x16x32_bf16(ah[rf], bh, acc[c][rf], 0, 0, 0);
                acc[c][rf] = __builtin_amdgcn_mfma_f32_16x16x32_bf16(al[rf], bh, acc[c][rf], 0, 0, 0);
                acc[c][rf] = __builtin_amdgcn_mfma_f32_16x16x32_bf16(ah[rf], bl, acc[c][rf], 0, 0, 0);
            }
        }
    }

    __syncthreads();   // all A ds_reads done; LDS reused for epilogue staging

    // epilogue: C/D layout col=lane&15, row=(lane>>4)*4+reg
    if constexpr (EPI == 0) {
#pragma unroll
        for (int c = 0; c < CTW; c++) {
            int col = (w * CTW + c) * 16 + mcol;
            float bv = b1[col];
#pragma unroll
            for (int rf = 0; rf < 4; rf++) {
#pragma unroll
                for (int r = 0; r < 4; r++) {
                    int row = rf * 16 + hk * 4 + r;
                    float v = gelu_erf(acc[c][rf][r] + bv);
                    unsigned short hb = f2bf(v);
                    int bo = row * 256 + col * 2;
                    *reinterpret_cast<unsigned short*>(&lds[swz(bo)])         = hb;
                    *reinterpret_cast<unsigned short*>(&lds[16384 + swz(bo)]) = f2bf(v - bf2f(hb));
                }
            }
        }
        __syncthreads();
#pragma unroll
        for (int i = 0; i < 8; i++) {
            int idx = t + i * 256;          // 2048 uint4: hi 0..1023, lo 1024..2047
            int pl = idx >> 10;
            int j = idx & 1023;
            int row = j >> 4;
            int gr = row0 + row;
            if (gr < N) {
                uint4 v = *reinterpret_cast<const uint4*>(&lds[pl * 16384 + swz(row * 256 + (j & 15) * 16)]);
                unsigned short* dp = pl ? o1lo : o1hi;
                *reinterpret_cast<uint4*>(dp + (size_t)gr * 128 + (j & 15) * 8) = v;
            }
        }
    } else {
#pragma unroll
        for (int c = 0; c < CTW; c++) {
            int ctg = w * CTW + c;
            bool isq = ctg < QCT;
            int ct = isq ? ctg : ctg - QCT;
            int col = ct * 16 + mcol;
            float bv = (isq ? b1 : b2)[col];
#pragma unroll
            for (int rf = 0; rf < 4; rf++) {
#pragma unroll
                for (int r = 0; r < 4; r++) {
                    int row = rf * 16 + hk * 4 + r;
                    int gr = row0 + row;
                    float v = acc[c][rf][r] + bv;
                    if (isq) {
                        if (gr < N) outq[(size_t)gr * C + col] = v;   // 4B x 16 lanes = full line
                    } else {
                        *reinterpret_cast<unsigned short*>(&lds[swz(row * 256 + col * 2)]) = f2bf(v);
                    }
                }
            }
        }
        __syncthreads();
        constexpr int SLOTS = C / 8;        // uint4 slots per row (16 or 8)
#pragma unroll
        for (int i = 0; i < (64 * SLOTS) / 256; i++) {
            int idx = t + i * 256;
            int row = idx / SLOTS;
            int sl = idx % SLOTS;
            int gr = row0 + row;
            if (gr < N)
                *reinterpret_cast<uint4*>(outp + (size_t)gr * C + sl * 8) =
                    *reinterpret_cast<const uint4*>(&lds[swz(row * 256 + sl * 16)]);
        }
    }
}

// ---------------- CSR build: atomic-free two-level counting sort -------------
// Coarse bin = dst >> 4 (16 nodes per bin), CB = ceil(N/16) <= 4096.
// 64 edge-blocks; gh[bin*64 + blk] = count (bin-major for linear scan).

__global__ __launch_bounds__(256) void hist_coarse(
    const int* __restrict__ dst, int* __restrict__ gh, int E, int CB)
{
    __shared__ int cnt[4096];
    const int blk = blockIdx.x;     // 0..63
    const int t = threadIdx.x;
    for (int b = t; b < CB; b += 256) cnt[b] = 0;
    __syncthreads();
    const int epb = (E + 63) / 64;
    const int s = blk * epb;
    const int e_ = (s + epb < E) ? s + epb : E;
    for (int i = s + t; i < e_; i += 256)
        atomicAdd(&cnt[dst[i] >> 4], 1);
    __syncthreads();
    for (int b = t; b < CB; b += 256)
        gh[b * 64 + blk] = cnt[b];
}

// hierarchical exclusive scan over M = CB*64 values: gh -> gscan
__global__ __launch_bounds__(256) void scan1_kernel(const int* __restrict__ gh,
                                                    int* __restrict__ gscan,
                                                    int* __restrict__ bsum, int M)
{
    __shared__ int lds[256];
    int t = threadIdx.x;
    int i = blockIdx.x * 256 + t;
    int v = (i < M) ? gh[i] : 0;
    lds[t] = v;
    __syncthreads();
    int x = v;
    for (int off = 1; off < 256; off <<= 1) {
        int y = (t >= off) ? lds[t - off] : 0;
        __syncthreads();
        x += y;
        lds[t] = x;
        __syncthreads();
    }
    if (i < M) gscan[i] = x - v;
    if (t == 255) bsum[blockIdx.x] = x;
}

__global__ __launch_bounds__(1024) void scan2_kernel(int* __restrict__ bsum, int NB)
{
    __shared__ int lds[1024];
    int t = threadIdx.x;
    int v = (t < NB) ? bsum[t] : 0;
    lds[t] = v;
    __syncthreads();
    int x = v;
    for (int off = 1; off < 1024; off <<= 1) {
        int y = (t >= off) ? lds[t - off] : 0;
        __syncthreads();
        x += y;
        lds[t] = x;
        __syncthreads();
    }
    if (t < NB) bsum[t] = x - v;
}

__global__ __launch_bounds__(256) void scan3_kernel(int* __restrict__ gscan,
                                                    const int* __restrict__ bsum, int M)
{
    int i = blockIdx.x * 256 + threadIdx.x;
    if (i < M) gscan[i] += bsum[blockIdx.x];
}

// scatter edges into coarse-bin-grouped (dst,src) pairs; LDS cursors only.
__global__ __launch_bounds__(256) void scatter_coarse(
    const int* __restrict__ src, const int* __restrict__ dst,
    const int* __restrict__ gscan, int2* __restrict__ pairs, int E, int CB)
{
    __shared__ int cur[4096];
    const int blk = blockIdx.x;     // 0..63
    const int t = threadIdx.x;
    for (int b = t; b < CB; b += 256)
        cur[b] = gscan[b * 64 + blk];
    __syncthreads();
    const int epb = (E + 63) / 64;
    const int s = blk * epb;
    const int e_ = (s + epb < E) ? s + epb : E;
    for (int i = s + t; i < e_; i += 256) {
        int d = dst[i];
        int sv = src[i];
        int pos = atomicAdd(&cur[d >> 4], 1);   // LDS atomic
        pairs[pos] = make_int2(d, sv);
    }
}

// one block per coarse bin: exact CSR within the bin's contiguous segment.
__global__ __launch_bounds__(256) void finalize_kernel(
    const int2* __restrict__ pairs, const int* __restrict__ gscan,
    int* __restrict__ offs, int* __restrict__ csr_src, int N, int E, int CB)
{
    const int c = blockIdx.x;
    const int t = threadIdx.x;
    __shared__ unsigned int cnt[8], rnk[8];
    __shared__ int pref[16];
    if (t < 8) { cnt[t] = 0u; rnk[t] = 0u; }
    __syncthreads();

    const int s  = gscan[c * 64];
    const int e_ = (c + 1 < CB) ? gscan[(c + 1) * 64] : E;
    const int base = c * 16;

    for (int i = s + t; i < e_; i += 256) {
        int d = pairs[i].x - base;    // 0..15
        atomicAdd(&cnt[d >> 1], 1u << ((d & 1) * 16));
    }
    __syncthreads();
    if (t == 0) {
        int run = s;
        for (int j = 0; j < 16; j++) {
            pref[j] = run;
            run += (int)((cnt[j >> 1] >> ((j & 1) * 16)) & 0xffffu);
        }
    }
    __syncthreads();
    if (t < 16 && base + t < N) offs[base + t] = pref[t];
    if (c == CB - 1 && t == 0) offs[N] = E;

    for (int i = s + t; i < e_; i += 256) {
        int2 pr = pairs[i];
        int d = pr.x - base;
        unsigned int old = atomicAdd(&rnk[d >> 1], 1u << ((d & 1) * 16));
        int r = (int)((old >> ((d & 1) * 16)) & 0xffffu);
        csr_src[pref[d] + r] = pr.y;
    }
}

// ---------------- fused GAT edge-softmax + aggregation -----------------------
// 16 lanes per dst node, 4 nodes per wave, 4 edges per group-iteration:
// 4 independent csr loads + 4 independent p-row gathers in flight (MLP=4),
// next-iteration csr indices prefetched. Score partial per edge =
// fma(d,0.6a)+fma(|d|,0.4a) (leaky(x)=0.6x+0.4|x|); 4 independent 4-stage
// DPP row_ror reduce chains. Inactive slots masked branchlessly via
// esm = act ? es : 0 (garbage reduces stay inside their own 16-lane group).
// EPI 0 (D=128): m2 = gelu(h+bvec) -> hi/lo bf16.  EPI 1 (D=64): fp32 out.
template <int D, int EPI>
__global__ __launch_bounds__(256) void gat_agg(
    const float* __restrict__ q, const unsigned short* __restrict__ p,
    const float* __restrict__ a, const float* __restrict__ bvec,
    const int* __restrict__ offs, const int* __restrict__ csr_src,
    float* __restrict__ out, unsigned short* __restrict__ mhi,
    unsigned short* __restrict__ mlo, int N)
{
    constexpr int VPL = D / 16;   // dims per lane: 8 (D=128) or 4 (D=64)
    const int t = threadIdx.x;
    const int lane = t & 63;
    const int sl = lane & 15;
    const int base = sl * VPL;
    const int node = blockIdx.x * 16 + ((t >> 6) << 2) + (lane >> 4);
    const bool valid = node < N;

    float qv[VPL], a6[VPL], a4[VPL], acc[VPL];
#pragma unroll
    for (int v = 0; v < VPL; v++) { qv[v] = 0.f; acc[v] = 0.f; }
    if (valid) {
        const float* qp = q + (size_t)node * D + base;
        float4 q0 = *reinterpret_cast<const float4*>(qp);
        qv[0] = q0.x; qv[1] = q0.y; qv[2] = q0.z; qv[3] = q0.w;
        if constexpr (VPL == 8) {
            float4 q1 = *reinterpret_cast<const float4*>(qp + 4);
            qv[4] = q1.x; qv[5] = q1.y; qv[6] = q1.z; qv[7] = q1.w;
        }
    }
#pragma unroll
    for (int v = 0; v < VPL; v++) {
        float av = a[base + v];
        a6[v] = 0.6f * av;
        a4[v] = 0.4f * av;
    }

    float denom = 0.f;
    int e  = valid ? offs[node] : 0;
    int e1 = valid ? offs[node + 1] : 0;

    // prologue: csr indices for the first 4-edge batch (clamped to a valid slot)
    int s0 = csr_src[(e + 0 < e1) ? e + 0 : 0];
    int s1 = csr_src[(e + 1 < e1) ? e + 1 : 0];
    int s2 = csr_src[(e + 2 < e1) ? e + 2 : 0];
    int s3 = csr_src[(e + 3 < e1) ? e + 3 : 0];

    float pv[4][VPL];

    while (__any(e < e1)) {
        const bool a0 = (e + 0) < e1, a1b = (e + 1) < e1,
                   a2 = (e + 2) < e1, a3 = (e + 3) < e1;

        // issue the 4 p-row gathers (independent; 16 lanes x 16B = one row)
        if constexpr (D == 128) {
            uint4 u0 = *reinterpret_cast<const uint4*>(p + (size_t)s0 * 128 + base);
            uint4 u1 = *reinterpret_cast<const uint4*>(p + (size_t)s1 * 128 + base);
            uint4 u2 = *reinterpret_cast<const uint4*>(p + (size_t)s2 * 128 + base);
            uint4 u3 = *reinterpret_cast<const uint4*>(p + (size_t)s3 * 128 + base);
            pv[0][0] = __uint_as_float(u0.x << 16); pv[0][1] = __uint_as_float(u0.x & 0xffff0000u);
            pv[0][2] = __uint_as_float(u0.y << 16); pv[0][3] = __uint_as_float(u0.y & 0xffff0000u);
            pv[0][4] = __uint_as_float(u0.z << 16); pv[0][5] = __uint_as_float(u0.z & 0xffff0000u);
            pv[0][6] = __uint_as_float(u0.w << 16); pv[0][7] = __uint_as_float(u0.w & 0xffff0000u);
            pv[1][0] = __uint_as_float(u1.x << 16); pv[1][1] = __uint_as_float(u1.x & 0xffff0000u);
            pv[1][2] = __uint_as_float(u1.y << 16); pv[1][3] = __uint_as_float(u1.y & 0xffff0000u);
            pv[1][4] = __uint_as_float(u1.z << 16); pv[1][5] = __uint_as_float(u1.z & 0xffff0000u);
            pv[1][6] = __uint_as_float(u1.w << 16); pv[1][7] = __uint_as_float(u1.w & 0xffff0000u);
            pv[2][0] = __uint_as_float(u2.x << 16); pv[2][1] = __uint_as_float(u2.x & 0xffff0000u);
            pv[2][2] = __uint_as_float(u2.y << 16); pv[2][3] = __uint_as_float(u2.y & 0xffff0000u);
            pv[2][4] = __uint_as_float(u2.z << 16); pv[2][5] = __uint_as_float(u2.z & 0xffff0000u);
            pv[2][6] = __uint_as_float(u2.w << 16); pv[2][7] = __uint_as_float(u2.w & 0xffff0000u);
            pv[3][0] = __uint_as_float(u3.x << 16); pv[3][1] = __uint_as_float(u3.x & 0xffff0000u);
            pv[3][2] = __uint_as_float(u3.y << 16); pv[3][3] = __uint_as_float(u3.y & 0xffff0000u);
            pv[3][4] = __uint_as_float(u3.z << 16); pv[3][5] = __uint_as_float(u3.z & 0xffff0000u);
            pv[3][6] = __uint_as_float(u3.w << 16); pv[3][7] = __uint_as_float(u3.w & 0xffff0000u);
        } else {
            uint2 u0 = *reinterpret_cast<const uint2*>(p + (size_t)s0 * 64 + base);
            uint2 u1 = *reinterpret_cast<const uint2*>(p + (size_t)s1 * 64 + base);
            uint2 u2 = *reinterpret_cast<const uint2*>(p + (size_t)s2 * 64 + base);
            uint2 u3 = *reinterpret_cast<const uint2*>(p + (size_t)s3 * 64 + base);
            pv[0][0] = __uint_as_float(u0.x << 16); pv[0][1] = __uint_as_float(u0.x & 0xffff0000u);
            pv[0][2] = __uint_as_float(u0.y << 16); pv[0][3] = __uint_as_float(u0.y & 0xffff0000u);
            pv[1][0] = __uint_as_float(u1.x << 16); pv[1][1] = __uint_as_float(u1.x & 0xffff0000u);
            pv[1][2] = __uint_as_float(u1.y << 16); pv[1][3] = __uint_as_float(u1.y & 0xffff0000u);
            pv[2][0] = __uint_as_float(u2.x << 16); pv[2][1] = __uint_as_float(u2.x & 0xffff0000u);
            pv[2][2] = __uint_as_float(u2.y << 16); pv[2][3] = __uint_as_float(u2.y & 0xffff0000u);
            pv[3][0] = __uint_as_float(u3.x << 16); pv[3][1] = __uint_as_float(u3.x & 0xffff0000u);
            pv[3][2] = __uint_as_float(u3.y << 16); pv[3][3] = __uint_as_float(u3.y & 0xffff0000u);
        }

        // prefetch next batch's csr indices (hides index->gather latency)
        const int en = e + 4;
        const int n0 = csr_src[(en + 0 < e1) ? en + 0 : 0];
        const int n1 = csr_src[(en + 1 < e1) ? en + 1 : 0];
        const int n2 = csr_src[(en + 2 < e1) ? en + 2 : 0];
        const int n3 = csr_src[(en + 3 < e1) ? en + 3 : 0];

        // score partials (4 independent fma chains)
        float pa0 = 0.f, pa1 = 0.f, pa2 = 0.f, pa3 = 0.f;
#pragma unroll
        for (int v = 0; v < VPL; v++) {
            float d0 = qv[v] + pv[0][v];
            float d1 = qv[v] + pv[1][v];
            float d2 = qv[v] + pv[2][v];
            float d3 = qv[v] + pv[3][v];
            pa0 = fmaf(d0, a6[v], pa0); pa0 = fmaf(fabsf(d0), a4[v], pa0);
            pa1 = fmaf(d1, a6[v], pa1); pa1 = fmaf(fabsf(d1), a4[v], pa1);
            pa2 = fmaf(d2, a6[v], pa2); pa2 = fmaf(fabsf(d2), a4[v], pa2);
            pa3 = fmaf(d3, a6[v], pa3); pa3 = fmaf(fabsf(d3), a4[v], pa3);
        }

        // 4 independent 16-lane reduce chains (pipeline through DPP)
        float r0 = row16_sum(pa0);
        float r1 = row16_sum(pa1);
        float r2 = row16_sum(pa2);
        float r3 = row16_sum(pa3);

        float esm0 = a0  ? __expf(r0) : 0.f;
        float esm1 = a1b ? __expf(r1) : 0.f;
        float esm2 = a2  ? __expf(r2) : 0.f;
        float esm3 = a3  ? __expf(r3) : 0.f;
        denom += (esm0 + esm1) + (esm2 + esm3);
#pragma unroll
        for (int v = 0; v < VPL; v++) {
            acc[v] = fmaf(esm0, pv[0][v], acc[v]);
            acc[v] = fmaf(esm1, pv[1][v], acc[v]);
            acc[v] = fmaf(esm2, pv[2][v], acc[v]);
            acc[v] = fmaf(esm3, pv[3][v], acc[v]);
        }

        e = en;
        s0 = n0; s1 = n1; s2 = n2; s3 = n3;
    }

    if (!valid) return;
    float inv = (denom != 0.f) ? 1.f / denom : 0.f;  // zero-degree -> agg = 0
    if constexpr (EPI == 0) {
        union { unsigned short us[8]; uint4 v; } H, L;
#pragma unroll
        for (int v = 0; v < VPL; v++) {
            float g = gelu_erf(acc[v] * inv + bvec[base + v]);
            H.us[v] = f2bf(g);
            L.us[v] = f2bf(g - bf2f(H.us[v]));
        }
        *reinterpret_cast<uint4*>(mhi + (size_t)node * 128 + base) = H.v;
        *reinterpret_cast<uint4*>(mlo + (size_t)node * 128 + base) = L.v;
    } else {
        union { float f[4]; float4 v; } O;
#pragma unroll
        for (int v = 0; v < VPL; v++) O.f[v] = acc[v] * inv + bvec[base + v];
        *reinterpret_cast<float4*>(out + (size_t)node * D + base) = O.v;
    }
}

// ---------------- launch ------------------------------------------------------
extern "C" void kernel_launch(void* const* d_in, const int* in_sizes, int n_in,
                              void* d_out, int out_size, void* d_ws, size_t ws_size,
                              hipStream_t stream)
{
    const float* x     = (const float*)d_in[0];
    const float* W0    = (const float*)d_in[1];
    const float* b0    = (const float*)d_in[2];
    const float* Wq1   = (const float*)d_in[3];
    const float* bq1   = (const float*)d_in[4];
    const float* Wp1   = (const float*)d_in[5];
    const float* bp1   = (const float*)d_in[6];
    const float* a1    = (const float*)d_in[7];
    const float* bg2   = (const float*)d_in[8];
    const float* Wq2   = (const float*)d_in[9];
    const float* bq2   = (const float*)d_in[10];
    const float* Wp2   = (const float*)d_in[11];
    const float* bp2   = (const float*)d_in[12];
    const float* a2    = (const float*)d_in[13];
    const float* b_out = (const float*)d_in[14];
    const int*   src   = (const int*)d_in[15];
    const int*   dst   = (const int*)d_in[16];

    const int N = in_sizes[0] / 128;
    const int E = in_sizes[15];
    float* out = (float*)d_out;

    // workspace carve
    float* q_buf        = (float*)d_ws;                      // N*128 f32
    unsigned short* pb  = (unsigned short*)(q_buf + (size_t)N * 128);  // N*128 bf16
    unsigned short* Mhi = pb + (size_t)N * 128;
    unsigned short* Mlo = Mhi + (size_t)N * 128;
    unsigned short* P0  = Mlo + (size_t)N * 128;
    unsigned short* Pq1 = P0  + 128 * 128 * 2;
    unsigned short* Pp1 = Pq1 + 128 * 128 * 2;
    unsigned short* Pq2 = Pp1 + 128 * 128 * 2;
    unsigned short* Pp2 = Pq2 + 128 * 64 * 2;
    int* offs    = (int*)(Pp2 + 128 * 64 * 2);
    int* csr_src = offs + (N + 2);
    const int CB = (N + 15) / 16;          // coarse bins (<= 4096 for N<=65536)
    const int M  = CB * 64;
    int* gh    = csr_src + E;
    int* gscan = gh + M;
    int* bsum  = gscan + M;                // 1024 ints
    // pairs aliases q_buf (dead until gemm layer-1); int2-aligned (base of ws)
    int2* pairs = (int2*)q_buf;

    const int NB1 = (M + 255) / 256;       // <= 1024

    // 1) weight prepack
    pack_w<<<dim3(64, 5), 256, 0, stream>>>(W0, Wq1, Wp1, Wq2, Wp2,
                                            P0, Pq1, Pp1, Pq2, Pp2);
    // 2-7) CSR build (atomic-free two-level counting sort)
    hist_coarse<<<64, 256, 0, stream>>>(dst, gh, E, CB);
    scan1_kernel<<<NB1, 256, 0, stream>>>(gh, gscan, bsum, M);
    scan2_kernel<<<1, 1024, 0, stream>>>(bsum, NB1);
    scan3_kernel<<<NB1, 256, 0, stream>>>(gscan, bsum, M);
    scatter_coarse<<<64, 256, 0, stream>>>(src, dst, gscan, pairs, E, CB);
    finalize_kernel<<<CB, 256, 0, stream>>>(pairs, gscan, offs, csr_src, N, E, CB);

    const int GB64 = (N + 63) / 64;
    const int GGAT = (N + 15) / 16;

    // 8) layer 0: m1 = gelu(x@W0 + b0) -> Mhi/Mlo
    mfma_gemm<128, false, 0><<<GB64, 256, 0, stream>>>(
        x, nullptr, nullptr, P0, b0, nullptr, nullptr,
        nullptr, nullptr, Mhi, Mlo, N);
    // 9) layer 1 projections: q1 fp32 + p1 bf16 in ONE pass over A
    mfma_gemm<128, true, 1><<<GB64, 256, 0, stream>>>(
        nullptr, Mhi, Mlo, Pq1, bq1, Pp1, bp1,
        q_buf, pb, nullptr, nullptr, N);
    // 10) layer 1 GAT -> m2 = gelu(h1 + bg2) -> Mhi/Mlo
    gat_agg<128, 0><<<GGAT, 256, 0, stream>>>(
        q_buf, pb, a1, bg2, offs, csr_src,
        nullptr, Mhi, Mlo, N);
    // 11) layer 2 projections: q2 fp32 + p2 bf16 in ONE pass over A
    mfma_gemm<64, true, 1><<<GB64, 256, 0, stream>>>(
        nullptr, Mhi, Mlo, Pq2, bq2, Pp2, bp2,
        q_buf, pb, nullptr, nullptr, N);
    // 12) layer 2 GAT + b_out -> d_out
    gat_agg<64, 1><<<GGAT, 256, 0, stream>>>(
        q_buf, pb, a2, b_out, offs, csr_src,
        out, nullptr, nullptr, N);
}